// Round 12
// baseline (1008.225 us; speedup 1.0000x reference)
//
#include <hip/hip_runtime.h>
#include <hip/hip_bf16.h>

#define EPS_BN 1e-5f

using short8  = __attribute__((ext_vector_type(8))) short;
using ushort8 = __attribute__((ext_vector_type(8))) unsigned short;
using f32x4   = __attribute__((ext_vector_type(4))) float;

typedef const __attribute__((address_space(1))) void* gas_ptr;
typedef __attribute__((address_space(3))) void* las_ptr;

__device__ inline float bf2f(unsigned short u) {
    union { unsigned i; float f; } c; c.i = ((unsigned)u) << 16; return c.f;
}
__device__ inline unsigned short f2bf(float f) {
    unsigned x = __float_as_uint(f);
    unsigned r = (x + 0x7FFF + ((x >> 16) & 1)) >> 16;   // RNE
    return (unsigned short)r;
}

// ---------------------------------------------------------------- utilities
__global__ void zero_i32(int* __restrict__ p, int n) {
    int i = blockIdx.x * blockDim.x + threadIdx.x;
    if (i < n) p[i] = 0;
}
__global__ void zero_f32(float* __restrict__ p, int n) {
    int i = blockIdx.x * blockDim.x + threadIdx.x;
    if (i < n) p[i] = 0.0f;
}

// zero row n of the gathered tables (pad target)
__global__ void zero_rows(unsigned short* __restrict__ xpad,
                          unsigned short* __restrict__ h1,
                          unsigned short* __restrict__ h2, int n) {
    int t = threadIdx.x;  // 256
    if (t < 128) xpad[(size_t)n * 128 + t] = 0;
    h1[(size_t)n * 256 + t] = 0;
    h2[(size_t)n * 256 + t] = 0;
}

// fp32 [R][C] -> bf16 [R][CP], zero-padded columns
__global__ void conv_w(const float* __restrict__ w, unsigned short* __restrict__ o,
                       int R, int C, int CP) {
    int t = blockIdx.x * blockDim.x + threadIdx.x;
    if (t >= R * CP) return;
    int r = t / CP, c = t % CP;
    o[t] = (c < C) ? f2bf(w[(size_t)r * C + c]) : (unsigned short)0;
}

// x [n][100] f32 -> xpad [n][128] bf16 (zero pad)
__global__ void conv_x_pad(const float* __restrict__ x, unsigned short* __restrict__ xp, int n) {
    int t = blockIdx.x * blockDim.x + threadIdx.x;
    if (t >= n * 32) return;
    int node = t >> 5, g = t & 31;
    int f0 = g * 4;
    ushort4 o;
    const float* xr = x + (size_t)node * 100;
    o.x = (f0 + 0 < 100) ? f2bf(xr[f0 + 0]) : 0;
    o.y = (f0 + 1 < 100) ? f2bf(xr[f0 + 1]) : 0;
    o.z = (f0 + 2 < 100) ? f2bf(xr[f0 + 2]) : 0;
    o.w = (f0 + 3 < 100) ? f2bf(xr[f0 + 3]) : 0;
    *(ushort4*)(xp + (size_t)node * 128 + f0) = o;
}

// ---------------------------------------------------------------- CSR build
__global__ void count_k(const int* __restrict__ dst, int* __restrict__ counts, int E) {
    int i = blockIdx.x * blockDim.x + threadIdx.x;
    if (i < E) atomicAdd(&counts[dst[i]], 1);
}

// exclusive scan of PADDED counts (pad each node's list to a multiple of 8)
__global__ void scan1(const int* __restrict__ counts, int* __restrict__ rp,
                      int* __restrict__ partials, int n) {
    __shared__ int s[256];
    int t = threadIdx.x;
    int i = blockIdx.x * 256 + t;
    int v = (i < n) ? ((counts[i] + 7) & ~7) : 0;
    s[t] = v;
    __syncthreads();
    for (int off = 1; off < 256; off <<= 1) {
        int u = (t >= off) ? s[t - off] : 0;
        __syncthreads();
        s[t] += u;
        __syncthreads();
    }
    if (i < n) rp[i] = s[t] - v;
    if (t == 255) partials[blockIdx.x] = s[255];
}

__global__ void scan2(int* __restrict__ partials, int nb) {
    __shared__ int s[512];
    int t = threadIdx.x;
    int v = (t < nb) ? partials[t] : 0;
    s[t] = v;
    __syncthreads();
    for (int off = 1; off < 512; off <<= 1) {
        int u = (t >= off) ? s[t - off] : 0;
        __syncthreads();
        s[t] += u;
        __syncthreads();
    }
    if (t < nb) partials[t] = s[t] - v;
}

__global__ void scan3(int* __restrict__ rp, const int* __restrict__ partials, int n) {
    int i = blockIdx.x * blockDim.x + threadIdx.x;
    if (i < n) rp[i] += partials[i >> 8];
}

__global__ void fill_k(const int* __restrict__ src, const int* __restrict__ dst,
                       const int* __restrict__ rp, int* __restrict__ cursor,
                       int* __restrict__ col, int E) {
    int i = blockIdx.x * blockDim.x + threadIdx.x;
    if (i < E) {
        int d = dst[i];
        int pos = atomicAdd(&cursor[d], 1);
        col[rp[d] + pos] = src[i];
    }
}

// write zero-row index into pad slots [deg, deg8)
__global__ void pad_fill(const int* __restrict__ rp, const int* __restrict__ cnt,
                         int* __restrict__ col, int n, int zrow) {
    int node = blockIdx.x * blockDim.x + threadIdx.x;
    if (node >= n) return;
    int d = cnt[node];
    int s = rp[node] + d;
    int e = rp[node] + ((d + 7) & ~7);
    for (int i = s; i < e; ++i) col[i] = zrow;
}

// --------------------------------------- fused SAGE layer (gather + MFMA)
// R6 GEMM skeleton with the aggregation fused in as a register prologue:
// 512 threads = 8 waves; block = 128 nodes; wave w -> 16 nodes, all DOUT cols.
// Prologue: wave mean-aggregates its 16 nodes directly into MFMA A-fragment
// layout (lane = node lcol, k-chunk lq): aggacc[KS][8] f32, padded CSR
// (multiple of 8, pads -> zero row n of xp). Then the R6 loop: W staged via
// global_load_lds (16B, lane-linear), double-buffered, ONE barrier per
// k-step; agg A-operand comes from registers (a2f[ks]).
template <int KTOT, int DOUT, bool HAS_AGG, bool RELU, bool STF32, bool STBF16>
__global__ __launch_bounds__(512, 4) void sage_fused(
    const unsigned short* __restrict__ xp,
    const int* __restrict__ rp, const int* __restrict__ cnt, const int* __restrict__ col,
    const unsigned short* __restrict__ Wr, const unsigned short* __restrict__ Wl,
    const float* __restrict__ bias,
    float* __restrict__ outf, unsigned short* __restrict__ outb, int n) {
    constexpr int CT = DOUT / 16;
    constexpr int NSRC = HAS_AGG ? 2 : 1;
    constexpr int FR = CT * 64;            // short8 units per source per kstep
    constexpr int CHUNKS = NSRC * CT;
    constexpr int CPW = CHUNKS / 8;
    constexpr int KS = KTOT / 32;
    constexpr int BUFSZ = CHUNKS * 512;    // ushorts per buffer
    __shared__ __align__(16) unsigned short lds[2 * BUFSZ];

    const int t = threadIdx.x;
    const int wave = t >> 6, lane = t & 63;
    const int node0 = blockIdx.x * 128 + wave * 16;
    const bool active = node0 < n;         // n % 16 == 0 -> all-or-none per wave
    const int lcol = lane & 15, lq = lane >> 4;

    auto stage = [&](int ks, int buf) {
        unsigned short* base = lds + buf * BUFSZ;
#pragma unroll
        for (int i = 0; i < CPW; ++i) {
            int chunk = wave * CPW + i;
            int srcSel = chunk / CT, ct = chunk % CT;
            const unsigned short* W = (srcSel == 0) ? Wr : Wl;
            const unsigned short* g = W + (size_t)(ct * 16 + lcol) * KTOT + ks * 32 + lq * 8;
            __builtin_amdgcn_global_load_lds((gas_ptr)g, (las_ptr)(lds + buf * BUFSZ + chunk * 512),
                                             16, 0, 0);
        }
        (void)base;
    };

    // issue first W panel before the prologue so it overlaps the gather
    stage(0, 0);

    // ---------- prologue: in-register mean aggregation ----------
    short8 a2f[KS];
    if constexpr (HAS_AGG) {
        float aggacc[KS][8];
#pragma unroll
        for (int ks = 0; ks < KS; ++ks)
#pragma unroll
            for (int j = 0; j < 8; ++j) aggacc[ks][j] = 0.0f;
        int deg = 0, s = 0;
        if (active) {
            int m = node0 + lcol;
            deg = cnt[m];
            s = rp[m];
        }
        int deg8 = (deg + 7) & ~7;
        const unsigned short* xq = xp + lq * 8;
        for (int i = 0; i < deg8; i += 2) {
            int r0 = col[s + i];
            int r1 = col[s + i + 1];
            const unsigned short* row0 = xq + (size_t)r0 * KTOT;
            const unsigned short* row1 = xq + (size_t)r1 * KTOT;
#pragma unroll
            for (int ks = 0; ks < KS; ++ks) {
                ushort8 v0 = *(const ushort8*)(row0 + ks * 32);
                ushort8 v1 = *(const ushort8*)(row1 + ks * 32);
#pragma unroll
                for (int j = 0; j < 8; ++j)
                    aggacc[ks][j] += bf2f(v0[j]) + bf2f(v1[j]);
            }
        }
        float sc = 1.0f / fmaxf((float)deg, 1.0f);
#pragma unroll
        for (int ks = 0; ks < KS; ++ks)
#pragma unroll
            for (int j = 0; j < 8; ++j)
                a2f[ks][j] = (short)f2bf(aggacc[ks][j] * sc);
    }

    f32x4 acc[CT];
#pragma unroll
    for (int c = 0; c < CT; ++c) {
        float b = bias[c * 16 + lcol];
        acc[c][0] = b; acc[c][1] = b; acc[c][2] = b; acc[c][3] = b;
    }

    const unsigned short* aRow = xp + (size_t)(node0 + lcol) * KTOT + lq * 8;

    __syncthreads();   // panel 0 ready (also syncs prologue completion)

#pragma unroll
    for (int ks = 0; ks < KS; ++ks) {
        if (ks + 1 < KS) stage(ks + 1, (ks + 1) & 1);
        if (active) {
            short8 a = *(const short8*)(aRow + ks * 32);
            const short8* bf = (const short8*)(lds + (ks & 1) * BUFSZ);
#pragma unroll
            for (int c = 0; c < CT; ++c)
                acc[c] = __builtin_amdgcn_mfma_f32_16x16x32_bf16(a, bf[c * 64 + lane], acc[c], 0, 0, 0);
            if constexpr (HAS_AGG) {
                const short8* bf2 = bf + FR;
#pragma unroll
                for (int c = 0; c < CT; ++c)
                    acc[c] = __builtin_amdgcn_mfma_f32_16x16x32_bf16(a2f[ks], bf2[c * 64 + lane], acc[c], 0, 0, 0);
            }
        }
        __syncthreads();
    }
    if (!active) return;

#pragma unroll
    for (int c = 0; c < CT; ++c) {
        f32x4 v = acc[c];
        if (RELU) {
            v[0] = fmaxf(v[0], 0.0f); v[1] = fmaxf(v[1], 0.0f);
            v[2] = fmaxf(v[2], 0.0f); v[3] = fmaxf(v[3], 0.0f);
        }
#pragma unroll
        for (int j = 0; j < 4; ++j) {
            size_t row = (size_t)node0 + lq * 4 + j;
            int colI = c * 16 + lcol;
            if (STF32) outf[row * DOUT + colI] = v[j];
            if (STBF16) outb[row * DOUT + colI] = f2bf(v[j]);
        }
    }
}

// ---------------------------------------------------------------- BatchNorm
__global__ void bn_partial(const float* __restrict__ z, float* __restrict__ sums, int n) {
    int f = threadIdx.x & 127;
    int half = threadIdx.x >> 7;
    float s = 0.0f, s2 = 0.0f;
    for (int row = blockIdx.x * 2 + half; row < n; row += gridDim.x * 2) {
        float v = z[(size_t)row * 128 + f];
        s += v; s2 += v * v;
    }
    __shared__ float ls[256], ls2[256];
    ls[threadIdx.x] = s; ls2[threadIdx.x] = s2;
    __syncthreads();
    if (half == 0) {
        atomicAdd(&sums[f], s + ls[128 + f]);
        atomicAdd(&sums[128 + f], s2 + ls2[128 + f]);
    }
}

__global__ void bn_finalize(const float* __restrict__ sums, const float* __restrict__ gamma,
                            const float* __restrict__ beta, float* __restrict__ params, int n) {
    int f = threadIdx.x;  // 128 threads
    float mu = sums[f] / (float)n;
    float var = sums[128 + f] / (float)n - mu * mu;
    float inv = rsqrtf(var + EPS_BN);
    float sc = gamma[f] * inv;
    params[f] = sc;
    params[128 + f] = beta[f] - mu * sc;
}

__global__ void bn_apply(float* __restrict__ z, const float* __restrict__ params, int total4) {
    int i = blockIdx.x * blockDim.x + threadIdx.x;
    for (; i < total4; i += gridDim.x * blockDim.x) {
        float4 v = ((float4*)z)[i];
        int f0 = (i & 31) * 4;
        v.x = v.x * params[f0 + 0] + params[128 + f0 + 0];
        v.y = v.y * params[f0 + 1] + params[128 + f0 + 1];
        v.z = v.z * params[f0 + 2] + params[128 + f0 + 2];
        v.w = v.w * params[f0 + 3] + params[128 + f0 + 3];
        ((float4*)z)[i] = v;
    }
}

// ---------------------------------------------------------------- launcher
extern "C" void kernel_launch(void* const* d_in, const int* in_sizes, int n_in,
                              void* d_out, int out_size, void* d_ws, size_t ws_size,
                              hipStream_t stream) {
    const float* x_in  = (const float*)d_in[0];
    const int*   ei    = (const int*)d_in[1];
    const float* Wl0   = (const float*)d_in[2];
    const float* bl0   = (const float*)d_in[3];
    const float* Wr0   = (const float*)d_in[4];
    const float* Wl1   = (const float*)d_in[5];
    const float* bl1   = (const float*)d_in[6];
    const float* Wr1   = (const float*)d_in[7];
    const float* Wl2   = (const float*)d_in[8];
    const float* bl2   = (const float*)d_in[9];
    const float* Wr2   = (const float*)d_in[10];
    const float* Wp    = (const float*)d_in[11];
    const float* bp    = (const float*)d_in[12];
    const float* gamma = (const float*)d_in[13];
    const float* beta  = (const float*)d_in[14];

    const int IN = 100, INP = 128, H = 256, OUT = 256, P = 128;
    const int n = in_sizes[0] / IN;          // 100000
    const int E = in_sizes[1] / 2;           // 1600000
    const int* src = ei;
    const int* dst = ei + E;

    size_t off = 0;
    auto alloc = [&](size_t bytes) -> char* {
        char* p = (char*)d_ws + off;
        off += (bytes + 255) & ~(size_t)255;
        return p;
    };
    int*   counts   = (int*)alloc((size_t)n * 4);
    int*   cursor   = (int*)alloc((size_t)n * 4);
    int*   rp       = (int*)alloc((size_t)(n + 1) * 4);
    int*   partials = (int*)alloc(512 * 4);
    int*   col      = (int*)alloc(((size_t)E + 8 * (size_t)n) * 4);
    unsigned short* Wl0b = (unsigned short*)alloc((size_t)H * INP * 2);
    unsigned short* Wr0b = (unsigned short*)alloc((size_t)H * INP * 2);
    unsigned short* Wl1b = (unsigned short*)alloc((size_t)H * H * 2);
    unsigned short* Wr1b = (unsigned short*)alloc((size_t)H * H * 2);
    unsigned short* Wl2b = (unsigned short*)alloc((size_t)OUT * H * 2);
    unsigned short* Wr2b = (unsigned short*)alloc((size_t)OUT * H * 2);
    unsigned short* Wpb  = (unsigned short*)alloc((size_t)P * OUT * 2);
    float* bnsums   = (float*)alloc(256 * 4);
    float* bnparams = (float*)alloc(256 * 4);
    // gathered tables get n+1 rows (row n = zero row, pad target)
    unsigned short* xpad = (unsigned short*)alloc((size_t)(n + 1) * INP * 2);
    unsigned short* h1b  = (unsigned short*)alloc((size_t)(n + 1) * H * 2);
    unsigned short* h2b  = (unsigned short*)alloc((size_t)(n + 1) * H * 2);
    unsigned short* xb2  = (unsigned short*)alloc((size_t)n * H * 2);
    (void)alloc((size_t)256 * 512);                      // OOB guard

    float* out_x = (float*)d_out;                  // [n][256] final x
    float* z     = out_x + (size_t)n * OUT;        // [n][128] projection/BN output

    const int nb = (n + 255) / 256;

    // --- CSR build (padded to multiples of 8, pad -> zero row n) ---
    zero_i32<<<nb, 256, 0, stream>>>(counts, n);
    zero_i32<<<nb, 256, 0, stream>>>(cursor, n);
    zero_f32<<<1, 256, 0, stream>>>(bnsums, 256);
    count_k<<<(E + 255) / 256, 256, 0, stream>>>(dst, counts, E);
    scan1<<<nb, 256, 0, stream>>>(counts, rp, partials, n);
    scan2<<<1, 512, 0, stream>>>(partials, nb);
    scan3<<<nb, 256, 0, stream>>>(rp, partials, n);
    fill_k<<<(E + 255) / 256, 256, 0, stream>>>(src, dst, rp, cursor, col, E);
    pad_fill<<<nb, 256, 0, stream>>>(rp, counts, col, n, n);

    // --- dtype conversions + zero rows ---
    conv_x_pad<<<(n * 32 + 255) / 256, 256, 0, stream>>>(x_in, xpad, n);
    zero_rows<<<1, 256, 0, stream>>>(xpad, h1b, h2b, n);
    conv_w<<<(H * INP + 255) / 256, 256, 0, stream>>>(Wl0, Wl0b, H, IN, INP);
    conv_w<<<(H * INP + 255) / 256, 256, 0, stream>>>(Wr0, Wr0b, H, IN, INP);
    conv_w<<<(H * H + 255) / 256, 256, 0, stream>>>(Wl1, Wl1b, H, H, H);
    conv_w<<<(H * H + 255) / 256, 256, 0, stream>>>(Wr1, Wr1b, H, H, H);
    conv_w<<<(OUT * H + 255) / 256, 256, 0, stream>>>(Wl2, Wl2b, OUT, H, H);
    conv_w<<<(OUT * H + 255) / 256, 256, 0, stream>>>(Wr2, Wr2b, OUT, H, H);
    conv_w<<<(P * OUT + 255) / 256, 256, 0, stream>>>(Wp, Wpb, P, OUT, OUT);

    const int gx = (n + 127) / 128;

    // --- layer 0: 128(pad) -> 256, relu (fused gather + GEMM) ---
    sage_fused<128, 256, true, true, false, true><<<gx, 512, 0, stream>>>(
        xpad, rp, counts, col, Wr0b, Wl0b, bl0, nullptr, h1b, n);

    // --- layer 1: 256 -> 256, relu ---
    sage_fused<256, 256, true, true, false, true><<<gx, 512, 0, stream>>>(
        h1b, rp, counts, col, Wr1b, Wl1b, bl1, nullptr, h2b, n);

    // --- layer 2: 256 -> 256, no relu; f32 -> d_out + bf16 copy for projection ---
    sage_fused<256, 256, true, false, true, true><<<gx, 512, 0, stream>>>(
        h2b, rp, counts, col, Wr2b, Wl2b, bl2, out_x, xb2, n);

    // --- projection head: 256 -> 128 (plain GEMM, reads bf16 xb2) ---
    sage_fused<256, 128, false, false, true, false><<<gx, 512, 0, stream>>>(
        xb2, rp, counts, col, Wpb, nullptr, bp, z, nullptr, n);

    // --- BatchNorm over z ---
    bn_partial<<<256, 256, 0, stream>>>(z, bnsums, n);
    bn_finalize<<<1, 128, 0, stream>>>(bnsums, gamma, beta, bnparams, n);
    bn_apply<<<2048, 256, 0, stream>>>(z, bnparams, n * (P / 4));
}